// Round 1
// baseline (4995.502 us; speedup 1.0000x reference)
//
#include <hip/hip_runtime.h>
#include <math.h>

#define B_  2
#define S_  1024
#define H_  4096
#define NH_ 32
#define HD_ 128
#define I_  11008
#define R_  2048   // B*S tokens

typedef __attribute__((ext_vector_type(4))) int i32x4;

// ---------------------------------------------------------------------------
// async global->LDS, 16B per lane. LDS dest is wave-uniform base (+lane*16 by HW).
__device__ __forceinline__ void gload_lds16(const void* g, void* l) {
    __builtin_amdgcn_global_load_lds(
        (const __attribute__((address_space(1))) unsigned int*)g,
        (__attribute__((address_space(3))) unsigned int*)l, 16, 0, 0);
}

// ---------------------------------------------------------------------------
// RMSNorm + per-tensor symmetric int8 quant (scale folded into w).
// One row (H=4096) per 256-thread block; 16 elems/thread.
__global__ __launch_bounds__(256)
void rmsnorm_quant_k(const float* __restrict__ x, const float* __restrict__ w,
                     signed char* __restrict__ out)
{
    __shared__ float red[4];
    const int tid = threadIdx.x;
    const long row = blockIdx.x;
    const float4* xr = (const float4*)(x + row * H_);
    float4 xv[4];
    float ss = 0.f;
#pragma unroll
    for (int i = 0; i < 4; ++i) {
        xv[i] = xr[tid + i * 256];
        ss += xv[i].x * xv[i].x + xv[i].y * xv[i].y
            + xv[i].z * xv[i].z + xv[i].w * xv[i].w;
    }
#pragma unroll
    for (int off = 32; off; off >>= 1) ss += __shfl_xor(ss, off);
    if ((tid & 63) == 0) red[tid >> 6] = ss;
    __syncthreads();
    const float tot = red[0] + red[1] + red[2] + red[3];
    const float sc = 1.f / sqrtf(tot * (1.f / (float)H_) + 1e-6f);
    const float4* wr = (const float4*)w;
    int* outi = (int*)(out + row * H_);
#pragma unroll
    for (int i = 0; i < 4; ++i) {
        const float4 wv = wr[tid + i * 256];
        const int b0 = (int)fminf(fmaxf(rintf(xv[i].x * sc * wv.x), -128.f), 127.f);
        const int b1 = (int)fminf(fmaxf(rintf(xv[i].y * sc * wv.y), -128.f), 127.f);
        const int b2 = (int)fminf(fmaxf(rintf(xv[i].z * sc * wv.z), -128.f), 127.f);
        const int b3 = (int)fminf(fmaxf(rintf(xv[i].w * sc * wv.w), -128.f), 127.f);
        outi[tid + i * 256] = (b0 & 255) | ((b1 & 255) << 8) | ((b2 & 255) << 16) | (b3 << 24);
    }
}

// ---------------------------------------------------------------------------
// int8 GEMM: C[M,N] = f32(A[M,K]i8 . W[N,K]i8^T) * scale + bias (+ residual)
// W arrives as int32 (sign-extended int8) -> packed to i8 during LDS staging.
// Tile 128x128, BK=64, 4 waves (2x2 of 64x64), mfma_i32_16x16x64_i8.
// LDS layout per operand: [kgrp 0..3][row 0..127][16B]  (conflict-free b128 reads)
__global__ __launch_bounds__(256, 2)
void gemm_i8(const signed char* __restrict__ A, const int* __restrict__ W,
             const float* __restrict__ scale_ptr, const float* __restrict__ bias,
             const float* __restrict__ residual, float* __restrict__ C,
             const int N, const int K)
{
    __shared__ __align__(16) signed char lsA[8192];
    __shared__ __align__(16) signed char lsB[8192];
    const int tid  = threadIdx.x;
    const int lane = tid & 63, wid = tid >> 6;
    const int bm = blockIdx.x << 7, bn = blockIdx.y << 7;
    const int wm = (wid >> 1) << 6, wn = (wid & 1) << 6;

    i32x4 acc[4][4];
#pragma unroll
    for (int m = 0; m < 4; ++m)
#pragma unroll
        for (int n = 0; n < 4; ++n) acc[m][n] = (i32x4){0, 0, 0, 0};

    // B staging mapping: thread -> (col in tile, 32-wide k half)
    const int brow = tid >> 1;
    const int bkh  = tid & 1;
    const long wrowoff = (long)(bn + brow) * K;
    // A staging: wave wid stages chunks {wid, wid+4}; chunk c: kgrp=c>>1, rowhalf=c&1
    const long arow0 = (long)(bm + ((wid    ) & 1) * 64 + lane) * K + ((wid    ) >> 1) * 16;
    const long arow1 = (long)(bm + ((wid + 4) & 1) * 64 + lane) * K + ((wid + 4) >> 1) * 16;

    const int nk = K >> 6;
    for (int kt = 0; kt < nk; ++kt) {
        const int k0 = kt << 6;
        gload_lds16(A + arow0 + k0, lsA + (wid    ) * 1024);
        gload_lds16(A + arow1 + k0, lsA + (wid + 4) * 1024);
        {
            const int4* gw = (const int4*)(W + wrowoff + k0 + bkh * 32);
            int p[8];
#pragma unroll
            for (int i = 0; i < 8; ++i) {
                const int4 w4 = gw[i];
                p[i] = (w4.x & 255) | ((w4.y & 255) << 8) | ((w4.z & 255) << 16) | (w4.w << 24);
            }
            *(i32x4*)(lsB + (bkh * 2 + 0) * 2048 + brow * 16) = (i32x4){p[0], p[1], p[2], p[3]};
            *(i32x4*)(lsB + (bkh * 2 + 1) * 2048 + brow * 16) = (i32x4){p[4], p[5], p[6], p[7]};
        }
        __syncthreads();   // drains global_load_lds (vmcnt) + ds_write (lgkmcnt)

        const int kg = (lane >> 4) * 2048, fr = (lane & 15) * 16;
        i32x4 af[4], bf[4];
#pragma unroll
        for (int m = 0; m < 4; ++m)
            af[m] = *(const i32x4*)(lsA + kg + wm * 16 + m * 256 + fr);
#pragma unroll
        for (int n = 0; n < 4; ++n)
            bf[n] = *(const i32x4*)(lsB + kg + wn * 16 + n * 256 + fr);
#pragma unroll
        for (int m = 0; m < 4; ++m)
#pragma unroll
            for (int n = 0; n < 4; ++n)
                acc[m][n] = __builtin_amdgcn_mfma_i32_16x16x64_i8(af[m], bf[n], acc[m][n], 0, 0, 0);
        __syncthreads();
    }

    // epilogue: C/D layout col=lane&15, row=(lane>>4)*4+r  (m89-verified)
    const float s = *scale_ptr;
    const int rq = (lane >> 4) * 4, fc = lane & 15;
#pragma unroll
    for (int m = 0; m < 4; ++m) {
#pragma unroll
        for (int n = 0; n < 4; ++n) {
            const int col = bn + wn + n * 16 + fc;
            const float bcol = bias[col];
#pragma unroll
            for (int r = 0; r < 4; ++r) {
                const int row = bm + wm + m * 16 + rq + r;
                float v = (float)acc[m][n][r] * s + bcol;
                if (residual) v += residual[(long)row * N + col];
                C[(long)row * N + col] = v;
            }
        }
    }
}

// ---------------------------------------------------------------------------
// RoPE applied in-place to q and k, layout [B,S,NH,HD] == [B,S,H] h-major.
__global__ __launch_bounds__(256)
void rope_k(float* __restrict__ q, float* __restrict__ k)
{
    const int row = blockIdx.x;            // token index b*S+s
    const int s = row & (S_ - 1);
    float* qr = q + (long)row * H_;
    float* kr = k + (long)row * H_;
    for (int t = threadIdx.x; t < NH_ * 64; t += 256) {
        const int nh = t >> 6, i = t & 63;
        const float inv = powf(10000.f, -(float)(2 * i) * (1.f / 128.f));
        const float f = (float)s * inv;
        float sn, c;
        sincosf(f, &sn, &c);
        const int base = nh * 128 + i;
        const float q0 = qr[base], q1 = qr[base + 64];
        qr[base]      = q0 * c - q1 * sn;
        qr[base + 64] = q1 * c + q0 * sn;
        const float k0 = kr[base], k1 = kr[base + 64];
        kr[base]      = k0 * c - k1 * sn;
        kr[base + 64] = k1 * c + k0 * sn;
    }
}

// ---------------------------------------------------------------------------
// Causal attention, fp32, online softmax. One wave per q-row (4 rows/block).
// o may alias q (each q-row is consumed only by its own wave before the write).
__global__ __launch_bounds__(256)
void attn_k(const float* q, const float* __restrict__ k,
            const float* __restrict__ v, float* o)
{
    const int lane = threadIdx.x & 63, wid = threadIdx.x >> 6;
    const long r = (long)blockIdx.x * 4 + wid;        // over (b,h,s), s fastest
    const int s = (int)(r & (S_ - 1));
    const long bh = r >> 10;
    const int h = (int)(bh & (NH_ - 1));
    const int b = (int)(bh >> 5);
    const float* qrow = q + ((long)(b * S_ + s) * NH_ + h) * HD_;
    const float q0 = qrow[lane], q1 = qrow[lane + 64];
    const long kvbase = ((long)(b * S_) * NH_ + h) * HD_;
    const float* kp = k + kvbase;
    const float* vp = v + kvbase;
    const long stride = (long)NH_ * HD_;
    float m = -3.0e38f, l = 0.f, o0 = 0.f, o1 = 0.f;
    const float sc = 0.08838834764831845f;  // 1/sqrt(128)
    for (int j = 0; j <= s; ++j) {
        const float* krj = kp + j * stride;
        float prt = q0 * krj[lane] + q1 * krj[lane + 64];
#pragma unroll
        for (int off = 32; off; off >>= 1) prt += __shfl_xor(prt, off);
        const float sj = prt * sc;
        const float mn = fmaxf(m, sj);
        const float cf = __expf(m - mn);
        const float p  = __expf(sj - mn);
        const float* vrj = vp + j * stride;
        l  = l  * cf + p;
        o0 = o0 * cf + p * vrj[lane];
        o1 = o1 * cf + p * vrj[lane + 64];
        m = mn;
    }
    const float inv = 1.f / l;
    float* orow = o + ((long)(b * S_ + s) * NH_ + h) * HD_;
    orow[lane]      = o0 * inv;
    orow[lane + 64] = o1 * inv;
}

// ---------------------------------------------------------------------------
// elementwise quant: out = clip(rint(x / scale)) as int8, 4 elems/thread
__global__ __launch_bounds__(256)
void quant_k(const float* __restrict__ x, const float* __restrict__ sp,
             signed char* __restrict__ out, const long n4)
{
    const float inv = 1.f / sp[0];
    const long i0 = (long)blockIdx.x * 256 + threadIdx.x;
    const long step = (long)gridDim.x * 256;
    for (long i = i0; i < n4; i += step) {
        const float4 xv = ((const float4*)x)[i];
        const int b0 = (int)fminf(fmaxf(rintf(xv.x * inv), -128.f), 127.f);
        const int b1 = (int)fminf(fmaxf(rintf(xv.y * inv), -128.f), 127.f);
        const int b2 = (int)fminf(fmaxf(rintf(xv.z * inv), -128.f), 127.f);
        const int b3 = (int)fminf(fmaxf(rintf(xv.w * inv), -128.f), 127.f);
        ((int*)out)[i] = (b0 & 255) | ((b1 & 255) << 8) | ((b2 & 255) << 16) | (b3 << 24);
    }
}

// a = silu(g)*u ; out = clip(rint(a / scale)) int8
__global__ __launch_bounds__(256)
void silu_mul_quant_k(const float* __restrict__ g, const float* __restrict__ u,
                      const float* __restrict__ sp, signed char* __restrict__ out,
                      const long n4)
{
    const float inv = 1.f / sp[0];
    const long i0 = (long)blockIdx.x * 256 + threadIdx.x;
    const long step = (long)gridDim.x * 256;
    for (long i = i0; i < n4; i += step) {
        const float4 gv = ((const float4*)g)[i];
        const float4 uv = ((const float4*)u)[i];
        const float a0 = gv.x / (1.f + __expf(-gv.x)) * uv.x;
        const float a1 = gv.y / (1.f + __expf(-gv.y)) * uv.y;
        const float a2 = gv.z / (1.f + __expf(-gv.z)) * uv.z;
        const float a3 = gv.w / (1.f + __expf(-gv.w)) * uv.w;
        const int b0 = (int)fminf(fmaxf(rintf(a0 * inv), -128.f), 127.f);
        const int b1 = (int)fminf(fmaxf(rintf(a1 * inv), -128.f), 127.f);
        const int b2 = (int)fminf(fmaxf(rintf(a2 * inv), -128.f), 127.f);
        const int b3 = (int)fminf(fmaxf(rintf(a3 * inv), -128.f), 127.f);
        ((int*)out)[i] = (b0 & 255) | ((b1 & 255) << 8) | ((b2 & 255) << 16) | (b3 << 24);
    }
}

// ---------------------------------------------------------------------------
extern "C" void kernel_launch(void* const* d_in, const int* in_sizes, int n_in,
                              void* d_out, int out_size, void* d_ws, size_t ws_size,
                              hipStream_t stream)
{
    const float* hidden = (const float*)d_in[0];
    const float* ln1 = (const float*)d_in[1];
    const float* ln2 = (const float*)d_in[2];
    const int* Wq = (const int*)d_in[3];
    const int* Wk = (const int*)d_in[4];
    const int* Wv = (const int*)d_in[5];
    const int* Wo = (const int*)d_in[6];
    const int* Wg = (const int*)d_in[7];
    const int* Wu = (const int*)d_in[8];
    const int* Wd = (const int*)d_in[9];
    const float* bq = (const float*)d_in[10];
    const float* bk = (const float*)d_in[11];
    const float* bv = (const float*)d_in[12];
    const float* bo = (const float*)d_in[13];
    const float* bg = (const float*)d_in[14];
    const float* bu = (const float*)d_in[15];
    const float* bd = (const float*)d_in[16];
    const float* sq = (const float*)d_in[17];
    const float* sk = (const float*)d_in[18];
    const float* sv = (const float*)d_in[19];
    const float* so = (const float*)d_in[20];
    const float* sg = (const float*)d_in[21];
    const float* su = (const float*)d_in[22];
    const float* sd = (const float*)d_in[23];
    const float* o_sc = (const float*)d_in[24];
    const float* d_sc = (const float*)d_in[25];

    // workspace layout (~236 MiB peak), dead-buffer reuse:
    //  [0,8M)    hq / oq / hq2 (i8);  [0,21.5M) aq (i8, after hq2 dead)
    //  [32M,64M) Q -> attn-out o (in place) -> h
    //  [64M,96M) K ; [96M,128M) V ; [64M,150M) G (after attn) ; [150M,236M) U
    char* ws = (char*)d_ws;
    signed char* HQ = (signed char*)ws;
    signed char* AQ = (signed char*)ws;
    float* Qb = (float*)(ws + ((size_t)32 << 20));
    float* Kb = (float*)(ws + ((size_t)64 << 20));
    float* Vb = (float*)(ws + ((size_t)96 << 20));
    float* Gb = (float*)(ws + ((size_t)64 << 20));
    float* Ub = (float*)(ws + ((size_t)150 << 20));
    float* Hb = Qb;
    float* out = (float*)d_out;

    const dim3 blk(256);
    const dim3 gH(R_ / 128, H_ / 128);   // (16,32)
    const dim3 gI(R_ / 128, I_ / 128);   // (16,86)

    rmsnorm_quant_k<<<R_, blk, 0, stream>>>(hidden, ln1, HQ);
    gemm_i8<<<gH, blk, 0, stream>>>(HQ, Wq, sq, bq, nullptr, Qb, H_, H_);
    gemm_i8<<<gH, blk, 0, stream>>>(HQ, Wk, sk, bk, nullptr, Kb, H_, H_);
    gemm_i8<<<gH, blk, 0, stream>>>(HQ, Wv, sv, bv, nullptr, Vb, H_, H_);
    rope_k<<<R_, blk, 0, stream>>>(Qb, Kb);
    attn_k<<<(B_ * NH_ * S_) / 4, blk, 0, stream>>>(Qb, Kb, Vb, Qb);
    quant_k<<<2048, blk, 0, stream>>>(Qb, o_sc, HQ, (long)R_ * H_ / 4);
    gemm_i8<<<gH, blk, 0, stream>>>(HQ, Wo, so, bo, hidden, Hb, H_, H_);
    rmsnorm_quant_k<<<R_, blk, 0, stream>>>(Hb, ln2, HQ);
    gemm_i8<<<gI, blk, 0, stream>>>(HQ, Wg, sg, bg, nullptr, Gb, I_, H_);
    gemm_i8<<<gI, blk, 0, stream>>>(HQ, Wu, su, bu, nullptr, Ub, I_, H_);
    silu_mul_quant_k<<<2048, blk, 0, stream>>>(Gb, Ub, d_sc, AQ, (long)R_ * I_ / 4);
    gemm_i8<<<gH, blk, 0, stream>>>(AQ, Wd, sd, bd, Hb, out, H_, I_);
}

// Round 2
// 2447.875 us; speedup vs baseline: 2.0408x; 2.0408x over previous
//
#include <hip/hip_runtime.h>
#include <math.h>

#define B_  2
#define S_  1024
#define H_  4096
#define NH_ 32
#define HD_ 128
#define I_  11008
#define R_  2048   // B*S tokens

typedef __attribute__((ext_vector_type(4))) int i32x4;
typedef __attribute__((ext_vector_type(4))) float f32x4;
typedef __attribute__((ext_vector_type(8))) short bf16x8;

// ---------------------------------------------------------------------------
// async global->LDS, 16B per lane. LDS dest is wave-uniform base (+lane*16 by HW).
__device__ __forceinline__ void gload_lds16(const void* g, void* l) {
    __builtin_amdgcn_global_load_lds(
        (const __attribute__((address_space(1))) unsigned int*)g,
        (__attribute__((address_space(3))) unsigned int*)l, 16, 0, 0);
}

__device__ __forceinline__ unsigned short f2bf(float f) {
    unsigned int u = __float_as_uint(f);
    u += 0x7fffu + ((u >> 16) & 1u);   // RNE
    return (unsigned short)(u >> 16);
}

// ---------------------------------------------------------------------------
// RMSNorm + per-tensor symmetric int8 quant (scale folded into w).
__global__ __launch_bounds__(256)
void rmsnorm_quant_k(const float* __restrict__ x, const float* __restrict__ w,
                     signed char* __restrict__ out)
{
    __shared__ float red[4];
    const int tid = threadIdx.x;
    const long row = blockIdx.x;
    const float4* xr = (const float4*)(x + row * H_);
    float4 xv[4];
    float ss = 0.f;
#pragma unroll
    for (int i = 0; i < 4; ++i) {
        xv[i] = xr[tid + i * 256];
        ss += xv[i].x * xv[i].x + xv[i].y * xv[i].y
            + xv[i].z * xv[i].z + xv[i].w * xv[i].w;
    }
#pragma unroll
    for (int off = 32; off; off >>= 1) ss += __shfl_xor(ss, off);
    if ((tid & 63) == 0) red[tid >> 6] = ss;
    __syncthreads();
    const float tot = red[0] + red[1] + red[2] + red[3];
    const float sc = 1.f / sqrtf(tot * (1.f / (float)H_) + 1e-6f);
    const float4* wr = (const float4*)w;
    int* outi = (int*)(out + row * H_);
#pragma unroll
    for (int i = 0; i < 4; ++i) {
        const float4 wv = wr[tid + i * 256];
        const int b0 = (int)fminf(fmaxf(rintf(xv[i].x * sc * wv.x), -128.f), 127.f);
        const int b1 = (int)fminf(fmaxf(rintf(xv[i].y * sc * wv.y), -128.f), 127.f);
        const int b2 = (int)fminf(fmaxf(rintf(xv[i].z * sc * wv.z), -128.f), 127.f);
        const int b3 = (int)fminf(fmaxf(rintf(xv[i].w * sc * wv.w), -128.f), 127.f);
        outi[tid + i * 256] = (b0 & 255) | ((b1 & 255) << 8) | ((b2 & 255) << 16) | (b3 << 24);
    }
}

// ---------------------------------------------------------------------------
// int8 GEMM: C[M,N] = f32(A[M,K]i8 . W[N,K]i8^T) * scale + bias (+ residual)
__global__ __launch_bounds__(256, 2)
void gemm_i8(const signed char* __restrict__ A, const int* __restrict__ W,
             const float* __restrict__ scale_ptr, const float* __restrict__ bias,
             const float* __restrict__ residual, float* __restrict__ C,
             const int N, const int K)
{
    __shared__ __align__(16) signed char lsA[8192];
    __shared__ __align__(16) signed char lsB[8192];
    const int tid  = threadIdx.x;
    const int lane = tid & 63, wid = tid >> 6;
    const int bm = blockIdx.x << 7, bn = blockIdx.y << 7;
    const int wm = (wid >> 1) << 6, wn = (wid & 1) << 6;

    i32x4 acc[4][4];
#pragma unroll
    for (int m = 0; m < 4; ++m)
#pragma unroll
        for (int n = 0; n < 4; ++n) acc[m][n] = (i32x4){0, 0, 0, 0};

    const int brow = tid >> 1;
    const int bkh  = tid & 1;
    const long wrowoff = (long)(bn + brow) * K;
    const long arow0 = (long)(bm + ((wid    ) & 1) * 64 + lane) * K + ((wid    ) >> 1) * 16;
    const long arow1 = (long)(bm + ((wid + 4) & 1) * 64 + lane) * K + ((wid + 4) >> 1) * 16;

    const int nk = K >> 6;
    for (int kt = 0; kt < nk; ++kt) {
        const int k0 = kt << 6;
        gload_lds16(A + arow0 + k0, lsA + (wid    ) * 1024);
        gload_lds16(A + arow1 + k0, lsA + (wid + 4) * 1024);
        {
            const int4* gw = (const int4*)(W + wrowoff + k0 + bkh * 32);
            int p[8];
#pragma unroll
            for (int i = 0; i < 8; ++i) {
                const int4 w4 = gw[i];
                p[i] = (w4.x & 255) | ((w4.y & 255) << 8) | ((w4.z & 255) << 16) | (w4.w << 24);
            }
            *(i32x4*)(lsB + (bkh * 2 + 0) * 2048 + brow * 16) = (i32x4){p[0], p[1], p[2], p[3]};
            *(i32x4*)(lsB + (bkh * 2 + 1) * 2048 + brow * 16) = (i32x4){p[4], p[5], p[6], p[7]};
        }
        __syncthreads();

        const int kg = (lane >> 4) * 2048, fr = (lane & 15) * 16;
        i32x4 af[4], bf[4];
#pragma unroll
        for (int m = 0; m < 4; ++m)
            af[m] = *(const i32x4*)(lsA + kg + wm * 16 + m * 256 + fr);
#pragma unroll
        for (int n = 0; n < 4; ++n)
            bf[n] = *(const i32x4*)(lsB + kg + wn * 16 + n * 256 + fr);
#pragma unroll
        for (int m = 0; m < 4; ++m)
#pragma unroll
            for (int n = 0; n < 4; ++n)
                acc[m][n] = __builtin_amdgcn_mfma_i32_16x16x64_i8(af[m], bf[n], acc[m][n], 0, 0, 0);
        __syncthreads();
    }

    const float s = *scale_ptr;
    const int rq = (lane >> 4) * 4, fc = lane & 15;
#pragma unroll
    for (int m = 0; m < 4; ++m) {
#pragma unroll
        for (int n = 0; n < 4; ++n) {
            const int col = bn + wn + n * 16 + fc;
            const float bcol = bias[col];
#pragma unroll
            for (int r = 0; r < 4; ++r) {
                const int row = bm + wm + m * 16 + rq + r;
                float v = (float)acc[m][n][r] * s + bcol;
                if (residual) v += residual[(long)row * N + col];
                C[(long)row * N + col] = v;
            }
        }
    }
}

// ---------------------------------------------------------------------------
// RoPE applied in-place to q and k, layout [B,S,NH,HD] == [B,S,H] h-major.
__global__ __launch_bounds__(256)
void rope_k(float* __restrict__ q, float* __restrict__ k)
{
    const int row = blockIdx.x;            // token index b*S+s
    const int s = row & (S_ - 1);
    float* qr = q + (long)row * H_;
    float* kr = k + (long)row * H_;
    for (int t = threadIdx.x; t < NH_ * 64; t += 256) {
        const int nh = t >> 6, i = t & 63;
        const float inv = powf(10000.f, -(float)(2 * i) * (1.f / 128.f));
        const float f = (float)s * inv;
        float sn, c;
        sincosf(f, &sn, &c);
        const int base = nh * 128 + i;
        const float q0 = qr[base], q1 = qr[base + 64];
        qr[base]      = q0 * c - q1 * sn;
        qr[base + 64] = q1 * c + q0 * sn;
        const float k0 = kr[base], k1 = kr[base + 64];
        kr[base]      = k0 * c - k1 * sn;
        kr[base + 64] = k1 * c + k0 * sn;
    }
}

// ---------------------------------------------------------------------------
// Flash attention, bf16 MFMA (16x16x32), fp32 online softmax.
// Block = 4 waves = one (b,h) x 64 q-rows; wave w owns 16 rows.
// K-tile 32 rows staged in LDS: K row-major XOR-swizzled; V transposed, 80B pitch.
// P re-layout C->A fragment via per-wave 1KB swizzled LDS buffer.
// o may alias q (Q is register-staged at block start; blocks touch disjoint regions).
__global__ __launch_bounds__(256, 2)
void attn_mfma_k(const float* __restrict__ q, const float* __restrict__ k,
                 const float* __restrict__ v, float* __restrict__ o)
{
    __shared__ __align__(16) char lsK[8192];        // [32 krow][128 d] bf16, XOR swizzle
    __shared__ __align__(16) char lsV[10240];       // V^T [128 d][40 pitch] bf16
    __shared__ __align__(16) char lsP[4][1024];     // per-wave P [16][32] bf16, XOR swizzle

    const int tid = threadIdx.x, lane = tid & 63, wid = tid >> 6;
    const int bid = blockIdx.x;
    const int qt = 15 - (bid >> 6);                 // reversed: long blocks first
    const int bh = bid & 63;
    const int b = bh >> 5, h = bh & 31;
    const int q0 = qt * 64;
    const int qw = q0 + wid * 16;                   // this wave's first q row

    const float* qbase = q + (long)(b * S_) * H_ + (long)h * HD_;
    const float* kbase = k + (long)(b * S_) * H_ + (long)h * HD_;
    const float* vbase = v + (long)(b * S_) * H_ + (long)h * HD_;

    const int frow = lane & 15, fgrp = lane >> 4;
    const float sc = 0.08838834764831845f;          // 1/sqrt(128), folded into Q

    // Q fragments: lane holds Q[frow][fgrp*8+j] per 32-wide d-chunk c
    bf16x8 qf[4];
    {
        const float* qr = qbase + (long)(qw + frow) * H_;
#pragma unroll
        for (int c = 0; c < 4; ++c) {
            const float4 a = *(const float4*)(qr + c * 32 + fgrp * 8);
            const float4 bq = *(const float4*)(qr + c * 32 + fgrp * 8 + 4);
            bf16x8 t;
            t[0] = (short)f2bf(a.x * sc);  t[1] = (short)f2bf(a.y * sc);
            t[2] = (short)f2bf(a.z * sc);  t[3] = (short)f2bf(a.w * sc);
            t[4] = (short)f2bf(bq.x * sc); t[5] = (short)f2bf(bq.y * sc);
            t[6] = (short)f2bf(bq.z * sc); t[7] = (short)f2bf(bq.w * sc);
            qf[c] = t;
        }
    }

    f32x4 oacc[8];
#pragma unroll
    for (int n2 = 0; n2 < 8; ++n2) oacc[n2] = (f32x4){0.f, 0.f, 0.f, 0.f};
    float mr[4] = {-1e30f, -1e30f, -1e30f, -1e30f};
    float lr[4] = {0.f, 0.f, 0.f, 0.f};

    const int nt = (q0 >> 5) + 2;
    for (int kt = 0; kt < nt; ++kt) {
        if (kt) __syncthreads();                    // prev tile's LDS reads done
        // ---- stage K, V tiles (32 rows x 128 d), fp32 -> bf16 ----
        {
            const float* kg = kbase + (long)(kt * 32) * H_;
            const float* vg = vbase + (long)(kt * 32) * H_;
#pragma unroll
            for (int i = 0; i < 4; ++i) {
                const int lin = i * 256 + tid;
                const int kr = lin >> 5;
                const int d4 = (lin & 31) * 4;
                const float4 kv = *(const float4*)(kg + (long)kr * H_ + d4);
                const float4 vv = *(const float4*)(vg + (long)kr * H_ + d4);
                ushort4 kb;
                kb.x = f2bf(kv.x); kb.y = f2bf(kv.y); kb.z = f2bf(kv.z); kb.w = f2bf(kv.w);
                *(ushort4*)(lsK + kr * 256 + ((d4 * 2) ^ ((kr & 7) << 4))) = kb;
                *(unsigned short*)(lsV + (d4 + 0) * 80 + kr * 2) = f2bf(vv.x);
                *(unsigned short*)(lsV + (d4 + 1) * 80 + kr * 2) = f2bf(vv.y);
                *(unsigned short*)(lsV + (d4 + 2) * 80 + kr * 2) = f2bf(vv.z);
                *(unsigned short*)(lsV + (d4 + 3) * 80 + kr * 2) = f2bf(vv.w);
            }
        }
        __syncthreads();

        if (kt * 32 <= qw + 15) {                   // tile not fully above diagonal
            // ---- QK^T: S(16x32) = Q(16x128) . K^T ----
            f32x4 s0 = (f32x4){0.f, 0.f, 0.f, 0.f};
            f32x4 s1 = (f32x4){0.f, 0.f, 0.f, 0.f};
            const int swz = (frow & 7) << 4;
#pragma unroll
            for (int c = 0; c < 4; ++c) {
                const int dby = c * 64 + fgrp * 16;
                const bf16x8 kfA = *(const bf16x8*)(lsK + frow * 256 + (dby ^ swz));
                const bf16x8 kfB = *(const bf16x8*)(lsK + (frow + 16) * 256 + (dby ^ swz));
                s0 = __builtin_amdgcn_mfma_f32_16x16x32_bf16(qf[c], kfA, s0, 0, 0, 0);
                s1 = __builtin_amdgcn_mfma_f32_16x16x32_bf16(qf[c], kfB, s1, 0, 0, 0);
            }

            // ---- online softmax (C layout: row=fgrp*4+r, col=frow / frow+16) ----
            const int colg0 = kt * 32 + frow;
            float cf[4];
#pragma unroll
            for (int r = 0; r < 4; ++r) {
                const int rowg = qw + fgrp * 4 + r;
                const float a0 = (colg0 <= rowg) ? s0[r] : -1e30f;
                const float a1 = (colg0 + 16 <= rowg) ? s1[r] : -1e30f;
                float mx = fmaxf(a0, a1);
#pragma unroll
                for (int off2 = 1; off2 < 16; off2 <<= 1) mx = fmaxf(mx, __shfl_xor(mx, off2));
                const float mnew = fmaxf(mr[r], mx);
                cf[r] = __expf(mr[r] - mnew);
                mr[r] = mnew;
                const float p0 = __expf(a0 - mnew);
                const float p1 = __expf(a1 - mnew);
                float sm = p0 + p1;
#pragma unroll
                for (int off2 = 1; off2 < 16; off2 <<= 1) sm += __shfl_xor(sm, off2);
                lr[r] = lr[r] * cf[r] + sm;
                const int row = fgrp * 4 + r;
                const int psw = (row & 3) << 4;
                *(unsigned short*)(lsP[wid] + row * 64 + ((frow * 2) ^ psw)) = f2bf(p0);
                *(unsigned short*)(lsP[wid] + row * 64 + (((16 + frow) * 2) ^ psw)) = f2bf(p1);
            }
            // rescale O
#pragma unroll
            for (int n2 = 0; n2 < 8; ++n2) {
#pragma unroll
                for (int r = 0; r < 4; ++r) oacc[n2][r] *= cf[r];
            }
            // ---- PV: O(16x128) += P(16x32) . V(32x128) ----
            const bf16x8 pf = *(const bf16x8*)(lsP[wid] + frow * 64 + ((fgrp * 16) ^ ((frow & 3) << 4)));
#pragma unroll
            for (int n2 = 0; n2 < 8; ++n2) {
                const bf16x8 vf = *(const bf16x8*)(lsV + (n2 * 16 + frow) * 80 + fgrp * 16);
                oacc[n2] = __builtin_amdgcn_mfma_f32_16x16x32_bf16(pf, vf, oacc[n2], 0, 0, 0);
            }
        }
    }

    // ---- epilogue: O /= l, write fp32 ----
    float inv[4];
#pragma unroll
    for (int r = 0; r < 4; ++r) inv[r] = 1.f / lr[r];
    float* ob = o + (long)(b * S_) * H_ + (long)h * HD_;
#pragma unroll
    for (int n2 = 0; n2 < 8; ++n2) {
#pragma unroll
        for (int r = 0; r < 4; ++r) {
            ob[(long)(qw + fgrp * 4 + r) * H_ + n2 * 16 + frow] = oacc[n2][r] * inv[r];
        }
    }
}

// ---------------------------------------------------------------------------
__global__ __launch_bounds__(256)
void quant_k(const float* __restrict__ x, const float* __restrict__ sp,
             signed char* __restrict__ out, const long n4)
{
    const float inv = 1.f / sp[0];
    const long i0 = (long)blockIdx.x * 256 + threadIdx.x;
    const long step = (long)gridDim.x * 256;
    for (long i = i0; i < n4; i += step) {
        const float4 xv = ((const float4*)x)[i];
        const int b0 = (int)fminf(fmaxf(rintf(xv.x * inv), -128.f), 127.f);
        const int b1 = (int)fminf(fmaxf(rintf(xv.y * inv), -128.f), 127.f);
        const int b2 = (int)fminf(fmaxf(rintf(xv.z * inv), -128.f), 127.f);
        const int b3 = (int)fminf(fmaxf(rintf(xv.w * inv), -128.f), 127.f);
        ((int*)out)[i] = (b0 & 255) | ((b1 & 255) << 8) | ((b2 & 255) << 16) | (b3 << 24);
    }
}

__global__ __launch_bounds__(256)
void silu_mul_quant_k(const float* __restrict__ g, const float* __restrict__ u,
                      const float* __restrict__ sp, signed char* __restrict__ out,
                      const long n4)
{
    const float inv = 1.f / sp[0];
    const long i0 = (long)blockIdx.x * 256 + threadIdx.x;
    const long step = (long)gridDim.x * 256;
    for (long i = i0; i < n4; i += step) {
        const float4 gv = ((const float4*)g)[i];
        const float4 uv = ((const float4*)u)[i];
        const float a0 = gv.x / (1.f + __expf(-gv.x)) * uv.x;
        const float a1 = gv.y / (1.f + __expf(-gv.y)) * uv.y;
        const float a2 = gv.z / (1.f + __expf(-gv.z)) * uv.z;
        const float a3 = gv.w / (1.f + __expf(-gv.w)) * uv.w;
        const int b0 = (int)fminf(fmaxf(rintf(a0 * inv), -128.f), 127.f);
        const int b1 = (int)fminf(fmaxf(rintf(a1 * inv), -128.f), 127.f);
        const int b2 = (int)fminf(fmaxf(rintf(a2 * inv), -128.f), 127.f);
        const int b3 = (int)fminf(fmaxf(rintf(a3 * inv), -128.f), 127.f);
        ((int*)out)[i] = (b0 & 255) | ((b1 & 255) << 8) | ((b2 & 255) << 16) | (b3 << 24);
    }
}

// ---------------------------------------------------------------------------
extern "C" void kernel_launch(void* const* d_in, const int* in_sizes, int n_in,
                              void* d_out, int out_size, void* d_ws, size_t ws_size,
                              hipStream_t stream)
{
    const float* hidden = (const float*)d_in[0];
    const float* ln1 = (const float*)d_in[1];
    const float* ln2 = (const float*)d_in[2];
    const int* Wq = (const int*)d_in[3];
    const int* Wk = (const int*)d_in[4];
    const int* Wv = (const int*)d_in[5];
    const int* Wo = (const int*)d_in[6];
    const int* Wg = (const int*)d_in[7];
    const int* Wu = (const int*)d_in[8];
    const int* Wd = (const int*)d_in[9];
    const float* bq = (const float*)d_in[10];
    const float* bk = (const float*)d_in[11];
    const float* bv = (const float*)d_in[12];
    const float* bo = (const float*)d_in[13];
    const float* bg = (const float*)d_in[14];
    const float* bu = (const float*)d_in[15];
    const float* bd = (const float*)d_in[16];
    const float* sq = (const float*)d_in[17];
    const float* sk = (const float*)d_in[18];
    const float* sv = (const float*)d_in[19];
    const float* so = (const float*)d_in[20];
    const float* sg = (const float*)d_in[21];
    const float* su = (const float*)d_in[22];
    const float* sd = (const float*)d_in[23];
    const float* o_sc = (const float*)d_in[24];
    const float* d_sc = (const float*)d_in[25];

    char* ws = (char*)d_ws;
    signed char* HQ = (signed char*)ws;
    signed char* AQ = (signed char*)ws;
    float* Qb = (float*)(ws + ((size_t)32 << 20));
    float* Kb = (float*)(ws + ((size_t)64 << 20));
    float* Vb = (float*)(ws + ((size_t)96 << 20));
    float* Gb = (float*)(ws + ((size_t)64 << 20));
    float* Ub = (float*)(ws + ((size_t)150 << 20));
    float* Hb = Qb;
    float* out = (float*)d_out;

    const dim3 blk(256);
    const dim3 gH(R_ / 128, H_ / 128);   // (16,32)
    const dim3 gI(R_ / 128, I_ / 128);   // (16,86)

    rmsnorm_quant_k<<<R_, blk, 0, stream>>>(hidden, ln1, HQ);
    gemm_i8<<<gH, blk, 0, stream>>>(HQ, Wq, sq, bq, nullptr, Qb, H_, H_);
    gemm_i8<<<gH, blk, 0, stream>>>(HQ, Wk, sk, bk, nullptr, Kb, H_, H_);
    gemm_i8<<<gH, blk, 0, stream>>>(HQ, Wv, sv, bv, nullptr, Vb, H_, H_);
    rope_k<<<R_, blk, 0, stream>>>(Qb, Kb);
    attn_mfma_k<<<B_ * NH_ * (S_ / 64), blk, 0, stream>>>(Qb, Kb, Vb, Qb);
    quant_k<<<2048, blk, 0, stream>>>(Qb, o_sc, HQ, (long)R_ * H_ / 4);
    gemm_i8<<<gH, blk, 0, stream>>>(HQ, Wo, so, bo, hidden, Hb, H_, H_);
    rmsnorm_quant_k<<<R_, blk, 0, stream>>>(Hb, ln2, HQ);
    gemm_i8<<<gI, blk, 0, stream>>>(HQ, Wg, sg, bg, nullptr, Gb, I_, H_);
    gemm_i8<<<gI, blk, 0, stream>>>(HQ, Wu, su, bu, nullptr, Ub, I_, H_);
    silu_mul_quant_k<<<2048, blk, 0, stream>>>(Gb, Ub, d_sc, AQ, (long)R_ * I_ / 4);
    gemm_i8<<<gH, blk, 0, stream>>>(AQ, Wd, sd, bd, Hb, out, H_, I_);
}